// Round 6
// baseline (351.332 us; speedup 1.0000x reference)
//
#include <hip/hip_runtime.h>
#include <hip/hip_fp16.h>
#include <stdint.h>

typedef _Float16 half_t;
typedef __attribute__((ext_vector_type(8))) _Float16 half8;   // MFMA A/B frag (4 VGPRs)
typedef __attribute__((ext_vector_type(16))) float f32x16;    // 32x32 MFMA C/D frag
typedef __attribute__((ext_vector_type(4)))  float float4v;

#define BM 256
#define BN 256
#define BK 64     // 8 chunks of 8 halves (16 B) per row
#define NTHR 512  // 8 waves

// ---------------------------------------------------------------------------
// R6: geometry change, not scheduling. R5 counters proved the kernel is
// LDS-instruction-throughput-bound: 96 ds_*_b128 per block-K-step x ~12cyc
// x 2 resident blocks = 2304 cyc == measured 2344 cyc per block-K-step;
// MFMA needs only 512 cyc (22%, == MfmaUtil). Scheduling fixes (R3-R5)
// couldn't move this because the LDS pipe itself is the serial resource.
//
// Fix: 8 waves, 256x256 block tile, 128x64 per wave (4x2 acc blocking of
// 32x32 frags). Reads/MFMA: 1.0 -> 0.75 (6 reads feed 8 MFMAs per k-slice);
// ds_writes and global fetch per FLOP halve (staging scales with tile
// perimeter). LDS instr per FLOP drops 1.5x on the binding resource.
// LDS 128KB (double-buffered) -> 1 block/CU, 8 waves = 2 waves/SIMD.
//
// Pipeline skeleton unchanged from R5 (proven correct): straight-line K-loop
// (last iter peeled), volatile asm global_load_dwordx4 staging pinned live
// across MFMA, s_waitcnt vmcnt(0) + sched_barrier(0) before cvt, ONE
// __syncthreads per K-step (hazard audit: step t reads buf[cur], writes
// buf[cur^1]; conflicting accesses to the same buffer are separated by the
// trailing barrier of the intervening step).
//
// quantize == fp32->f16 RNE cvt (reference e5m10 quantize incl. denormals),
// applied on stage for A/B and inline for bias.
// C[m][n] = sum_k qA[m][k]*qB[n][k] + q(bias[n]); mfma_f32_32x32x16_f16;
// XOR k-chunk swizzle on LDS; XCD-aware block swizzle (2-wide bn strip/XCD).
// ---------------------------------------------------------------------------
__global__ __launch_bounds__(512, 1)
void gemm_qf16_8w(const float* __restrict__ A, const float* __restrict__ B,
                  const float* __restrict__ bias, float* __restrict__ C,
                  int M, int N, int K) {
    __shared__ half_t sA[2][BM * BK];   // 2 x 32 KB
    __shared__ half_t sB[2][BN * BK];   // 2 x 32 KB

    const int t    = threadIdx.x;
    const int lane = t & 63;
    const int wave = t >> 6;            // 0..7
    const int wm   = (wave >> 2) * 128; // {0,128}
    const int wn   = (wave & 3) * 64;   // {0,64,128,192}

    // XCD-aware 1-D -> 2-D block swizzle (specialized for the 16x16 grid)
    const int nbx = N / BN, nby = M / BM;
    int bxi, byi;
    {
        const int b = blockIdx.x;
        if (nbx == 16 && nby == 16) {
            const int xcd = b & 7;      // round-robin assumption, perf-only
            const int s   = b >> 3;     // 0..31
            bxi = xcd * 2 + (s & 1);    // 2-wide bn strip per XCD
            byi = s >> 1;
        } else {
            bxi = b % nbx;
            byi = b / nbx;
        }
    }
    const int bm = byi * BM;
    const int bn = bxi * BN;

    // staging: 2048 16B-f16-chunks per matrix per K-step, 4 per thread;
    // chunk c: row = c>>3, LDS pos = c&7, global k-chunk = (c&7) ^ (row&7)
    const float* pa[4];
    const float* pb[4];
    int ldsoff[4];
    #pragma unroll
    for (int s = 0; s < 4; ++s) {
        const int c   = t + NTHR * s;
        const int row = c >> 3;
        const int kc  = (c & 7) ^ (row & 7);
        pa[s] = A + (long)(bm + row) * K + kc * 8;
        pb[s] = B + (long)(bn + row) * K + kc * 8;
        ldsoff[s] = c * 8;
    }

    f32x16 acc[4][2] = {};

    const int ml = lane & 31;   // m (or n) within 32-tile
    const int kg = lane >> 5;   // which 8-k half of the MFMA's K=16
    const int sw = ml & 7;      // row component of the XOR swizzle

    float4v ra0[4], ra1[4], rb0[4], rb1[4];

    const int NT = K / BK;

    // ---- prologue: synchronous load + cvt + write buf 0 ----
    #pragma unroll
    for (int s = 0; s < 4; ++s) {
        ra0[s] = *(const float4v*)(pa[s]);
        ra1[s] = *(const float4v*)(pa[s] + 4);
        rb0[s] = *(const float4v*)(pb[s]);
        rb1[s] = *(const float4v*)(pb[s] + 4);
        pa[s] += BK; pb[s] += BK;
    }
    #pragma unroll
    for (int s = 0; s < 4; ++s) {
        half8 ha, hb;
        ha[0]=(half_t)ra0[s][0]; ha[1]=(half_t)ra0[s][1]; ha[2]=(half_t)ra0[s][2]; ha[3]=(half_t)ra0[s][3];
        ha[4]=(half_t)ra1[s][0]; ha[5]=(half_t)ra1[s][1]; ha[6]=(half_t)ra1[s][2]; ha[7]=(half_t)ra1[s][3];
        hb[0]=(half_t)rb0[s][0]; hb[1]=(half_t)rb0[s][1]; hb[2]=(half_t)rb0[s][2]; hb[3]=(half_t)rb0[s][3];
        hb[4]=(half_t)rb1[s][0]; hb[5]=(half_t)rb1[s][1]; hb[6]=(half_t)rb1[s][2]; hb[7]=(half_t)rb1[s][3];
        *(half8*)&sA[0][ldsoff[s]] = ha;
        *(half8*)&sB[0][ldsoff[s]] = hb;
    }
    __syncthreads();

    int cur = 0;
    for (int kt = 0; kt < NT - 1; ++kt) {
        // ---- issue next tile's loads: volatile asm, un-sinkable, outputs
        //      pinned in VGPRs until the cvt block after MFMA ----
        #pragma unroll
        for (int s = 0; s < 4; ++s) {
            asm volatile("global_load_dwordx4 %0, %2, off\n\t"
                         "global_load_dwordx4 %1, %2, off offset:16"
                         : "=&v"(ra0[s]), "=&v"(ra1[s])
                         : "v"(pa[s])
                         : "memory");
            asm volatile("global_load_dwordx4 %0, %2, off\n\t"
                         "global_load_dwordx4 %1, %2, off offset:16"
                         : "=&v"(rb0[s]), "=&v"(rb1[s])
                         : "v"(pb[s])
                         : "memory");
            pa[s] += BK; pb[s] += BK;
        }
        __builtin_amdgcn_sched_barrier(0);

        // ---- MFMA phase over lds[cur]: 4 k-slices x (6 reads, 8 MFMAs) ----
        #pragma unroll
        for (int ks = 0; ks < 4; ++ks) {
            const int cp = 2 * ks + kg;                    // k-chunk 0..7
            half8 a[4], b[2];
            #pragma unroll
            for (int i = 0; i < 4; ++i)
                a[i] = *(const half8*)&sA[cur][((wm + 32*i + ml) * 8 + (cp ^ sw)) * 8];
            #pragma unroll
            for (int j = 0; j < 2; ++j)
                b[j] = *(const half8*)&sB[cur][((wn + 32*j + ml) * 8 + (cp ^ sw)) * 8];
            #pragma unroll
            for (int i = 0; i < 4; ++i)
                #pragma unroll
                for (int j = 0; j < 2; ++j)
                    acc[i][j] = __builtin_amdgcn_mfma_f32_32x32x16_f16(a[i], b[j], acc[i][j], 0, 0, 0);
        }

        // ---- drain the asm loads, then cvt + write other buffer ----
        asm volatile("s_waitcnt vmcnt(0)" ::: "memory");
        __builtin_amdgcn_sched_barrier(0);   // rule #18: no cvt hoisting
        {
            const int nxt = cur ^ 1;
            #pragma unroll
            for (int s = 0; s < 4; ++s) {
                half8 ha, hb;
                ha[0]=(half_t)ra0[s][0]; ha[1]=(half_t)ra0[s][1]; ha[2]=(half_t)ra0[s][2]; ha[3]=(half_t)ra0[s][3];
                ha[4]=(half_t)ra1[s][0]; ha[5]=(half_t)ra1[s][1]; ha[6]=(half_t)ra1[s][2]; ha[7]=(half_t)ra1[s][3];
                hb[0]=(half_t)rb0[s][0]; hb[1]=(half_t)rb0[s][1]; hb[2]=(half_t)rb0[s][2]; hb[3]=(half_t)rb0[s][3];
                hb[4]=(half_t)rb1[s][0]; hb[5]=(half_t)rb1[s][1]; hb[6]=(half_t)rb1[s][2]; hb[7]=(half_t)rb1[s][3];
                *(half8*)&sA[nxt][ldsoff[s]] = ha;
                *(half8*)&sB[nxt][ldsoff[s]] = hb;
            }
        }
        __syncthreads();
        cur ^= 1;
    }

    // ---- final tile: MFMA only ----
    #pragma unroll
    for (int ks = 0; ks < 4; ++ks) {
        const int cp = 2 * ks + kg;
        half8 a[4], b[2];
        #pragma unroll
        for (int i = 0; i < 4; ++i)
            a[i] = *(const half8*)&sA[cur][((wm + 32*i + ml) * 8 + (cp ^ sw)) * 8];
        #pragma unroll
        for (int j = 0; j < 2; ++j)
            b[j] = *(const half8*)&sB[cur][((wn + 32*j + ml) * 8 + (cp ^ sw)) * 8];
        #pragma unroll
        for (int i = 0; i < 4; ++i)
            #pragma unroll
            for (int j = 0; j < 2; ++j)
                acc[i][j] = __builtin_amdgcn_mfma_f32_32x32x16_f16(a[i], b[j], acc[i][j], 0, 0, 0);
    }

    // Epilogue. 32x32 C/D layout [m74/m101]: col = lane&31,
    // row = (reg&3) + 8*(reg>>2) + 4*(lane>>5)
    const int cl  = lane & 31;
    const int rbs = 4 * (lane >> 5);
    #pragma unroll
    for (int j = 0; j < 2; ++j) {
        const int col = bn + wn + j * 32 + cl;
        const float bq = (float)(half_t)bias[col];   // inline bias quantize
        #pragma unroll
        for (int i = 0; i < 4; ++i) {
            #pragma unroll
            for (int r = 0; r < 16; ++r) {
                const int row = bm + wm + i * 32 + (r & 3) + 8 * (r >> 2) + rbs;
                C[(long)row * N + col] = acc[i][j][r] + bq;
            }
        }
    }
}

extern "C" void kernel_launch(void* const* d_in, const int* in_sizes, int n_in,
                              void* d_out, int out_size, void* d_ws, size_t ws_size,
                              hipStream_t stream) {
    const float* x    = (const float*)d_in[0];
    const float* w    = (const float*)d_in[1];
    const float* bias = (const float*)d_in[2];
    float* out = (float*)d_out;

    const int OUT = in_sizes[2];
    const int IN  = in_sizes[1] / OUT;
    const int M   = in_sizes[0] / IN;
    const int N   = OUT, K = IN;

    dim3 grid((N / BN) * (M / BM));
    gemm_qf16_8w<<<grid, NTHR, 0, stream>>>(x, w, bias, out, M, N, K);
    (void)d_ws; (void)ws_size; (void)n_in; (void)out_size;
}

// Round 7
// 334.576 us; speedup vs baseline: 1.0501x; 1.0501x over previous
//
#include <hip/hip_runtime.h>
#include <hip/hip_fp16.h>
#include <stdint.h>

typedef _Float16 half_t;
typedef __attribute__((ext_vector_type(8))) _Float16 half8;   // MFMA A/B frag (4 VGPRs)
typedef __attribute__((ext_vector_type(16))) float f32x16;    // 32x32 MFMA C/D frag
typedef __attribute__((ext_vector_type(4)))  float float4v;

#define BM 256
#define BN 256
#define BK 64     // 8 chunks of 8 halves (16 B) per row
#define NTHR 512  // 8 waves

// counted waitcnt (immediate must be a literal in the asm string)
#define VMCNT(n) asm volatile("s_waitcnt vmcnt(" #n ")" ::: "memory")

// ---------------------------------------------------------------------------
// R7: counted-vmcnt phase interleave (T3+T4+T5) on the R6 geometry.
//
// R6 post-mortem: LDS pipe only ~35% busy (3072 cyc of LDS work vs 8900
// cyc measured per K-step) -> not LDS-bound; the serial chain
// [loads -> MFMA -> vmcnt(0) FULL drain -> cvt -> write -> barrier] is the
// cost: drain+cvt+write (~3-4K cyc) had zero MFMA overlap. Fix per m218
// (counted-vs-drain0 = +38..73%): split the MFMA phase into 4 k-slices and
// drain ONE staging group per slice with vmcnt(12-4g) -- never 0 until the
// last group, which has had the whole MFMA phase to land. sched_barrier(0)
// after each vmcnt (rule #18: cvts depend on asm DEFS, not the wait, and
// would hoist). setprio(1) around MFMA clusters (T5: pays at phase-split).
//
// Per-K-step instruction-order per wave:
//   issue 16 staging loads (4 groups x [2xA dwordx4, 2xB dwordx4])
//   slice0: 6 ds_read + 8 MFMA
//   for s=1..3: vmcnt(12-4(s-1)); cvt+write group s-1; slice s reads+MFMA
//   vmcnt(0); cvt+write group 3; __syncthreads
// Hazard audit unchanged from R5/R6: one barrier per step suffices
// (writes target buf[cur^1]; all reads of it completed before the previous
// step's trailing barrier).
//
// quantize == fp32->f16 RNE cvt (reference e5m10 quantize incl. denormals),
// on stage for A/B, inline for bias.
// C[m][n] = sum_k qA[m][k]*qB[n][k] + q(bias[n]); mfma_f32_32x32x16_f16;
// 8 waves, 128x64 per wave (4x2 of 32x32); XOR k-chunk LDS swizzle;
// XCD-aware block swizzle (2-wide bn strip per XCD, perf-only).
// ---------------------------------------------------------------------------
__global__ __launch_bounds__(512, 1)
void gemm_qf16_ph(const float* __restrict__ A, const float* __restrict__ B,
                  const float* __restrict__ bias, float* __restrict__ C,
                  int M, int N, int K) {
    __shared__ half_t sA[2][BM * BK];   // 2 x 32 KB
    __shared__ half_t sB[2][BN * BK];   // 2 x 32 KB

    const int t    = threadIdx.x;
    const int lane = t & 63;
    const int wave = t >> 6;            // 0..7
    const int wm   = (wave >> 2) * 128; // {0,128}
    const int wn   = (wave & 3) * 64;   // {0,64,128,192}

    // XCD-aware 1-D -> 2-D block swizzle (specialized for the 16x16 grid)
    const int nbx = N / BN, nby = M / BM;
    int bxi, byi;
    {
        const int b = blockIdx.x;
        if (nbx == 16 && nby == 16) {
            const int xcd = b & 7;      // round-robin assumption, perf-only
            const int s   = b >> 3;     // 0..31
            bxi = xcd * 2 + (s & 1);    // 2-wide bn strip per XCD
            byi = s >> 1;
        } else {
            bxi = b % nbx;
            byi = b / nbx;
        }
    }
    const int bm = byi * BM;
    const int bn = bxi * BN;

    // staging: 2048 16B-f16-chunks per matrix per K-step, 4 per thread;
    // chunk c: row = c>>3, LDS pos = c&7, global k-chunk = (c&7) ^ (row&7)
    const float* pa[4];
    const float* pb[4];
    int ldsoff[4];
    #pragma unroll
    for (int s = 0; s < 4; ++s) {
        const int c   = t + NTHR * s;
        const int row = c >> 3;
        const int kc  = (c & 7) ^ (row & 7);
        pa[s] = A + (long)(bm + row) * K + kc * 8;
        pb[s] = B + (long)(bn + row) * K + kc * 8;
        ldsoff[s] = c * 8;
    }

    f32x16 acc[4][2] = {};

    const int ml = lane & 31;   // m (or n) within 32-tile
    const int kg = lane >> 5;   // which 8-k half of the MFMA's K=16
    const int sw = ml & 7;      // row component of the XOR swizzle

    float4v ra0[4], ra1[4], rb0[4], rb1[4];

    const int NT = K / BK;

    // ---- prologue: synchronous load + cvt + write buf 0 ----
    #pragma unroll
    for (int s = 0; s < 4; ++s) {
        ra0[s] = *(const float4v*)(pa[s]);
        ra1[s] = *(const float4v*)(pa[s] + 4);
        rb0[s] = *(const float4v*)(pb[s]);
        rb1[s] = *(const float4v*)(pb[s] + 4);
        pa[s] += BK; pb[s] += BK;
    }
    #pragma unroll
    for (int s = 0; s < 4; ++s) {
        half8 ha, hb;
        ha[0]=(half_t)ra0[s][0]; ha[1]=(half_t)ra0[s][1]; ha[2]=(half_t)ra0[s][2]; ha[3]=(half_t)ra0[s][3];
        ha[4]=(half_t)ra1[s][0]; ha[5]=(half_t)ra1[s][1]; ha[6]=(half_t)ra1[s][2]; ha[7]=(half_t)ra1[s][3];
        hb[0]=(half_t)rb0[s][0]; hb[1]=(half_t)rb0[s][1]; hb[2]=(half_t)rb0[s][2]; hb[3]=(half_t)rb0[s][3];
        hb[4]=(half_t)rb1[s][0]; hb[5]=(half_t)rb1[s][1]; hb[6]=(half_t)rb1[s][2]; hb[7]=(half_t)rb1[s][3];
        *(half8*)&sA[0][ldsoff[s]] = ha;
        *(half8*)&sB[0][ldsoff[s]] = hb;
    }
    // normalize the vmcnt counter before entering the counted-wait loop
    VMCNT(0);
    __syncthreads();

    // per-slice MFMA over buf `cur`, slice index ks (compile-time)
    #define SLICE(ks)                                                          \
        do {                                                                   \
            const int cp = 2 * (ks) + kg;                                      \
            half8 a_[4], b_[2];                                                \
            _Pragma("unroll")                                                  \
            for (int i = 0; i < 4; ++i)                                        \
                a_[i] = *(const half8*)&sA[cur][((wm + 32*i + ml) * 8 + (cp ^ sw)) * 8]; \
            _Pragma("unroll")                                                  \
            for (int j = 0; j < 2; ++j)                                        \
                b_[j] = *(const half8*)&sB[cur][((wn + 32*j + ml) * 8 + (cp ^ sw)) * 8]; \
            __builtin_amdgcn_s_setprio(1);                                     \
            _Pragma("unroll")                                                  \
            for (int i = 0; i < 4; ++i)                                        \
                _Pragma("unroll")                                              \
                for (int j = 0; j < 2; ++j)                                    \
                    acc[i][j] = __builtin_amdgcn_mfma_f32_32x32x16_f16(a_[i], b_[j], acc[i][j], 0, 0, 0); \
            __builtin_amdgcn_s_setprio(0);                                     \
        } while (0)

    // cvt + ds_write staging group g into buf `nxt` (g compile-time)
    #define CVTWR(g)                                                           \
        do {                                                                   \
            half8 ha, hb;                                                      \
            ha[0]=(half_t)ra0[g][0]; ha[1]=(half_t)ra0[g][1]; ha[2]=(half_t)ra0[g][2]; ha[3]=(half_t)ra0[g][3]; \
            ha[4]=(half_t)ra1[g][0]; ha[5]=(half_t)ra1[g][1]; ha[6]=(half_t)ra1[g][2]; ha[7]=(half_t)ra1[g][3]; \
            hb[0]=(half_t)rb0[g][0]; hb[1]=(half_t)rb0[g][1]; hb[2]=(half_t)rb0[g][2]; hb[3]=(half_t)rb0[g][3]; \
            hb[4]=(half_t)rb1[g][0]; hb[5]=(half_t)rb1[g][1]; hb[6]=(half_t)rb1[g][2]; hb[7]=(half_t)rb1[g][3]; \
            *(half8*)&sA[nxt][ldsoff[g]] = ha;                                 \
            *(half8*)&sB[nxt][ldsoff[g]] = hb;                                 \
        } while (0)

    int cur = 0;
    for (int kt = 0; kt < NT - 1; ++kt) {
        const int nxt = cur ^ 1;

        // ---- issue next tile's 16 staging loads (4 groups x 4 instrs) ----
        #pragma unroll
        for (int s = 0; s < 4; ++s) {
            asm volatile("global_load_dwordx4 %0, %2, off\n\t"
                         "global_load_dwordx4 %1, %2, off offset:16"
                         : "=&v"(ra0[s]), "=&v"(ra1[s])
                         : "v"(pa[s])
                         : "memory");
            asm volatile("global_load_dwordx4 %0, %2, off\n\t"
                         "global_load_dwordx4 %1, %2, off offset:16"
                         : "=&v"(rb0[s]), "=&v"(rb1[s])
                         : "v"(pb[s])
                         : "memory");
            pa[s] += BK; pb[s] += BK;
        }
        __builtin_amdgcn_sched_barrier(0);

        // ---- slice 0: compute only (give group 0's loads time to land) ----
        SLICE(0);

        // ---- slice 1..3: drain one group, cvt+write it, then compute ----
        VMCNT(12);                                // group 0 (instrs 0..3) done
        __builtin_amdgcn_sched_barrier(0);        // rule #18
        CVTWR(0);
        SLICE(1);

        VMCNT(8);                                 // group 1 done
        __builtin_amdgcn_sched_barrier(0);
        CVTWR(1);
        SLICE(2);

        VMCNT(4);                                 // group 2 done
        __builtin_amdgcn_sched_barrier(0);
        CVTWR(2);
        SLICE(3);

        VMCNT(0);                                 // group 3 done
        __builtin_amdgcn_sched_barrier(0);
        CVTWR(3);

        __syncthreads();
        cur ^= 1;
    }

    // ---- final tile: MFMA only ----
    SLICE(0); SLICE(1); SLICE(2); SLICE(3);

    // Epilogue. 32x32 C/D layout [m74/m101]: col = lane&31,
    // row = (reg&3) + 8*(reg>>2) + 4*(lane>>5)
    const int cl  = lane & 31;
    const int rbs = 4 * (lane >> 5);
    #pragma unroll
    for (int j = 0; j < 2; ++j) {
        const int col = bn + wn + j * 32 + cl;
        const float bq = (float)(half_t)bias[col];   // inline bias quantize
        #pragma unroll
        for (int i = 0; i < 4; ++i) {
            #pragma unroll
            for (int r = 0; r < 16; ++r) {
                const int row = bm + wm + i * 32 + (r & 3) + 8 * (r >> 2) + rbs;
                C[(long)row * N + col] = acc[i][j][r] + bq;
            }
        }
    }
    #undef SLICE
    #undef CVTWR
}

extern "C" void kernel_launch(void* const* d_in, const int* in_sizes, int n_in,
                              void* d_out, int out_size, void* d_ws, size_t ws_size,
                              hipStream_t stream) {
    const float* x    = (const float*)d_in[0];
    const float* w    = (const float*)d_in[1];
    const float* bias = (const float*)d_in[2];
    float* out = (float*)d_out;

    const int OUT = in_sizes[2];
    const int IN  = in_sizes[1] / OUT;
    const int M   = in_sizes[0] / IN;
    const int N   = OUT, K = IN;

    dim3 grid((N / BN) * (M / BM));
    gemm_qf16_ph<<<grid, NTHR, 0, stream>>>(x, w, bias, out, M, N, K);
    (void)d_ws; (void)ws_size; (void)n_in; (void)out_size;
}